// Round 16
// baseline (213.159 us; speedup 1.0000x reference)
//
#include <hip/hip_runtime.h>
#include <hip/hip_bf16.h>
#include <math.h>

typedef unsigned short u16;
typedef unsigned int u32;
typedef unsigned long long u64;
typedef __attribute__((ext_vector_type(8))) _Float16 f16x8;
typedef __attribute__((ext_vector_type(4))) float f32x4;

#define B_   8
#define C_   256
#define HW_  4096
#define N_   32768
#define K_   8192

// ---- ws layout (bytes) ----
#define O_LOSSP 0ULL            // 512 doubles
#define O_E2    16384ULL        // 8192 f32
#define O_ZN2   49152ULL        // 32768 f32
#define O_IDX   180224ULL       // 32768 i32
#define O_AP    311296ULL       // 256 tiles * 8 chunks * 8KB (f16)
#define O_BP    17088512ULL     // 64 tiles * 8 chunks * 8KB (f16)
#define O_CAND  21282816ULL     // 32768*128*2 u32
#define WS_NEED 54837248ULL

#define THRESH_T 9e-5f

// LDS/tile byte swizzle: slot(row) = (row>>1)&3. Store K-group u4 at byte
// (u4*16)^(GSWZ(r)<<4); read group g at (g*16)^(GSWZ(r)<<4).
// Conflict-free for the 16-row fragment ds_read pattern (r8: BANK_CONFLICT=0).
#define GSWZ(r) (((r) >> 1) & 3)

__device__ __forceinline__ u16 f2h(float f) {
    _Float16 h = (_Float16)f;                 // v_cvt_f16_f32, RNE, deterministic
    return __builtin_bit_cast(u16, h);
}

__device__ __forceinline__ void gload16(const void* g, void* l) {
    __builtin_amdgcn_global_load_lds((const __attribute__((address_space(1))) void*)g,
                                     (__attribute__((address_space(3))) void*)l, 16, 0, 0);
}

// Tile layout (both Ap and Bp): [tile(128 rows)][chunk kc8 of 8][128 rows x 64B]

// =============== fused prep: blocks 0..127 -> codebook, 128..639 -> z ========
// (verified rounds 9-15)
__global__ __launch_bounds__(256) void vq_prep(const float* __restrict__ z,
                                               const float* __restrict__ cb,
                                               u16* __restrict__ Ap,
                                               u16* __restrict__ Bp,
                                               float* __restrict__ zn2g,
                                               float* __restrict__ e2g) {
    __shared__ float zl[128][65];
    const int tid = threadIdx.x;

    if (blockIdx.x < 128) {
        // ---- prep_cb: B_prep f16 (e scaled 2^13) + e2 ----
        const int k0 = blockIdx.x * 64;
        const int r = tid >> 2;
        const int u4 = tid & 3;
        const int k = k0 + r;
        const int r7 = k & 127;
        double eacc = 0.0;
        #pragma unroll
        for (int kc8 = 0; kc8 < 8; ++kc8) {
            const float* src = cb + (size_t)k * C_ + kc8 * 32 + u4 * 8;
            float4 v0 = *(const float4*)(src);
            float4 v1 = *(const float4*)(src + 4);
            float vals[8] = { v0.x, v0.y, v0.z, v0.w, v1.x, v1.y, v1.z, v1.w };
            u16 tmp[8];
            #pragma unroll
            for (int j = 0; j < 8; ++j) {
                eacc += (double)vals[j] * (double)vals[j];
                tmp[j] = f2h(vals[j] * 8192.0f);   // exact pow2 scale, then RNE
            }
            char* dst = (char*)Bp + ((size_t)((k >> 7) * 8 + kc8)) * 8192
                      + r7 * 64 + ((u4 * 16) ^ (GSWZ(r7) << 4));
            *(uint4*)dst = *(uint4*)tmp;
        }
        eacc += __shfl_xor(eacc, 1);
        eacc += __shfl_xor(eacc, 2);
        if (u4 == 0) e2g[k] = (float)eacc;
        return;
    }

    // ---- prep_z: A_prep f16 + zn2 ----
    const int bidz = blockIdx.x - 128;            // 0..511
    const int bb = bidz >> 6;
    const int hwc = bidz & 63;
    const int hw0 = hwc * 64;
    const int n0 = bb * HW_ + hw0;
    const int r = tid >> 2;         // 0..63 row within block
    const int u4 = tid & 3;         // K-group slot
    const int n = n0 + r;
    const int r7 = n & 127;         // row within 128-row tile
    double zacc = 0.0;

    for (int h = 0; h < 2; ++h) {
        __syncthreads();
        for (int c0 = 0; c0 < 128; c0 += 4) {
            int c = c0 + (tid >> 6);
            zl[c][tid & 63] = z[((size_t)(bb * C_ + h * 128 + c)) * HW_ + hw0 + (tid & 63)];
        }
        __syncthreads();
        // Ap chunks kc8 = h*4 + q ; local c = q*32 + u4*8 + j
        #pragma unroll
        for (int q = 0; q < 4; ++q) {
            u16 tmp[8];
            #pragma unroll
            for (int j = 0; j < 8; ++j) {
                float f = zl[q * 32 + u4 * 8 + j][r];
                zacc += (double)f * (double)f;
                tmp[j] = f2h(f);
            }
            char* dst = (char*)Ap + ((size_t)((n >> 7) * 8 + h * 4 + q)) * 8192
                      + r7 * 64 + ((u4 * 16) ^ (GSWZ(r7) << 4));
            *(uint4*)dst = *(uint4*)tmp;
        }
    }
    // reduce zn2 across the 4 u4-lanes of each row
    zacc += __shfl_xor(zacc, 1);
    zacc += __shfl_xor(zacc, 2);
    if (u4 == 0) zn2g[n] = (float)zacc;
}

// =============== main f16 MFMA scorer: top-2 per (row, 64-codes) =============
// r8 geometry (128x128, 4 waves 2x2, BK=32) with a 3-BUFFER SINGLE-BARRIER
// counted-vmcnt pipeline:
//   iter kc: vmcnt(4) [chunk kc landed; kc+1 stays in flight] + lgkmcnt(0)
//            [free: own reads already consumed] -> s_barrier ->
//            STAGE(buf (kc+2)%3 = (kc-1)%3, chunk kc+2) -> COMPUTE(buf kc%3).
// Overwrite safety: buf (kc-1)%3's last readers ran COMPUTE(kc-1); their MFMAs
// precede s_barrier in program order and can only issue after the compiler's
// lgkmcnt waits retire the ds_reads -> crossing barrier(kc) => reads consumed.
// 2-deep prefetch survives the barrier (no vmcnt(0) drain in steady state).
__global__ __launch_bounds__(256) void vq_gemm_top2(const u16* __restrict__ Ap,
                                                    const u16* __restrict__ Bp,
                                                    u32* __restrict__ cand) {
    __shared__ char lds[49152];          // 3 bufs x {codes 8K, z 8K}
    const int tid = threadIdx.x;
    const int lane = tid & 63, wid = tid >> 6;
    const int wm = wid >> 1, wn = wid & 1;
    const int l15 = lane & 15, l4 = lane >> 4;

    // L2-aware order: XCD owns 8 n_tiles; 8 consecutive blocks share one m-tile.
    const int raw = blockIdx.x;
    const int m_tile = raw >> 6;                         // 0..255
    const int n_tile = (raw & 7) * 8 + ((raw >> 3) & 7); // 0..63

    f32x4 acc[4][4];
    #pragma unroll
    for (int i = 0; i < 4; ++i)
        #pragma unroll
        for (int j = 0; j < 4; ++j) acc[i][j] = (f32x4){0.f, 0.f, 0.f, 0.f};

    int rc[4], rz[4], xc[4], xz[4];
    #pragma unroll
    for (int f = 0; f < 4; ++f) {
        rc[f] = wm * 64 + f * 16 + l15;
        rz[f] = wn * 64 + f * 16 + l15;
        xc[f] = GSWZ(rc[f]) << 4;
        xz[f] = GSWZ(rz[f]) << 4;
    }
    const int ob = l4 * 16;

    const char* codes_src = (const char*)Bp + (size_t)n_tile * 65536;
    const char* z_src     = (const char*)Ap + (size_t)m_tile * 65536;

    #define STAGE(buf, kc)                                                        \
        do {                                                                      \
            const char* cs_ = codes_src + (size_t)(kc) * 8192;                    \
            const char* zs_ = z_src + (size_t)(kc) * 8192;                        \
            char* lb_ = lds + (buf) * 16384;                                      \
            gload16(cs_ + tid * 16, lb_ + tid * 16);                              \
            gload16(cs_ + 4096 + tid * 16, lb_ + 4096 + tid * 16);                \
            gload16(zs_ + tid * 16, lb_ + 8192 + tid * 16);                       \
            gload16(zs_ + 4096 + tid * 16, lb_ + 12288 + tid * 16);               \
        } while (0)

    #define COMPUTE(buf)                                                          \
        do {                                                                      \
            const char* base_ = lds + (buf) * 16384;                              \
            f16x8 la[4], lb[4];                                                   \
            _Pragma("unroll")                                                     \
            for (int f = 0; f < 4; ++f) {                                         \
                la[f] = *(const f16x8*)(base_ + rc[f] * 64 + (ob ^ xc[f]));       \
                lb[f] = *(const f16x8*)(base_ + 8192 + rz[f] * 64 + (ob ^ xz[f]));\
            }                                                                     \
            _Pragma("unroll")                                                     \
            for (int fm = 0; fm < 4; ++fm)                                        \
                _Pragma("unroll")                                                 \
                for (int fn = 0; fn < 4; ++fn)                                    \
                    acc[fm][fn] = __builtin_amdgcn_mfma_f32_16x16x32_f16(         \
                        la[fm], lb[fn], acc[fm][fn], 0, 0, 0);                    \
        } while (0)

    #define FENCE() __builtin_amdgcn_sched_barrier(0)

    STAGE(0, 0);
    STAGE(1, 1);
    #pragma unroll
    for (int kc = 0; kc < 8; ++kc) {
        if (kc < 7) { asm volatile("s_waitcnt vmcnt(4)" ::: "memory"); }
        else        { asm volatile("s_waitcnt vmcnt(0)" ::: "memory"); }
        asm volatile("s_waitcnt lgkmcnt(0)" ::: "memory");   // free (already 0)
        FENCE();
        __builtin_amdgcn_s_barrier();
        FENCE();
        if (kc < 6) STAGE((kc + 2) % 3, kc + 2);   // buf (kc-1)%3: readers done
        COMPUTE(kc % 3);
    }

    #undef STAGE
    #undef COMPUTE
    #undef FENCE

    // epilogue: w = 0.5 - s_scaled*2^-12 (positive -> u32 order == float order);
    // clear low 6 mantissa bits, pack 6-bit in-tile idx, track top-2 via min/max.
    const int ktile = n_tile * 2 + wm;
    #pragma unroll
    for (int fn = 0; fn < 4; ++fn) {
        u32 m1 = 0xFFFFFFFFu, m2 = 0xFFFFFFFFu;
        #pragma unroll
        for (int fm = 0; fm < 4; ++fm) {
            #pragma unroll
            for (int rv = 0; rv < 4; ++rv) {
                float w = fmaf(acc[fm][fn][rv], -0x1p-12f, 0.5f);
                u32 p = (__float_as_uint(w) & ~63u) | (u32)(fm * 16 + l4 * 4 + rv);
                u32 t = m1 > p ? m1 : p;
                m1 = m1 < p ? m1 : p;
                m2 = m2 < t ? m2 : t;
            }
        }
        #pragma unroll
        for (int off = 16; off <= 32; off <<= 1) {
            u32 b1 = __shfl_xor(m1, off);
            u32 b2 = __shfl_xor(m2, off);
            u32 t = m1 > b1 ? m1 : b1;
            m1 = m1 < b1 ? m1 : b1;
            u32 s2 = m2 < b2 ? m2 : b2;
            m2 = s2 < t ? s2 : t;
        }
        if (l4 == 0) {
            int rowg = m_tile * 128 + wn * 64 + fn * 16 + l15;
            *(uint2*)(cand + (size_t)rowg * 256 + ktile * 2) = make_uint2(m1, m2);
        }
    }
}

// =============== pick: min + threshold + exact fp64 rescue + idx out =========
// wave per row. Fast path: exactly 1 candidate under thr -> it IS the argmin.
// Slow path reads z directly (strided gather; bit-identical fp64 rescue).
__global__ __launch_bounds__(256) void vq_pick(const u32* __restrict__ cand,
                                               const float* __restrict__ z,
                                               const float* __restrict__ cb,
                                               const float* __restrict__ e2g,
                                               const float* __restrict__ zn2g,
                                               int* __restrict__ idxg,
                                               float* __restrict__ out) {
    const int lane = threadIdx.x & 63, wid = threadIdx.x >> 6;
    const int row = blockIdx.x * 4 + wid;
    const uint4 e = ((const uint4*)(cand + (size_t)row * 256))[lane];
    u32 m = e.x < e.y ? e.x : e.y;
    u32 mzw = e.z < e.w ? e.z : e.w;
    m = m < mzw ? m : mzw;
    #pragma unroll
    for (int off = 32; off >= 1; off >>= 1) {
        u32 o = __shfl_xor(m, off);
        m = o < m ? o : m;
    }
    const float thr = __uint_as_float(m & ~63u) + THRESH_T;
    const u32 ev[4] = { e.x, e.y, e.z, e.w };
    u64 msk[4];
    int tot = 0;
    #pragma unroll
    for (int j = 0; j < 4; ++j) {
        msk[j] = __ballot(__uint_as_float(ev[j] & ~63u) <= thr);
        tot += __popcll((unsigned long long)msk[j]);
    }
    int bk;
    if (tot == 1) {
        const int j = msk[0] ? 0 : (msk[1] ? 1 : (msk[2] ? 2 : 3));
        const int l = __ffsll((unsigned long long)msk[j]) - 1;
        const u32 val = __shfl(ev[j], l);
        bk = ((l * 4 + j) >> 1) * 64 + (int)(val & 63u);
    } else {
        const int bb = row >> 12;
        const int hw = row & 4095;
        const float* zr = z + (size_t)(bb * C_) * HW_ + hw;
        float4 zv;
        zv.x = zr[(size_t)(lane * 4 + 0) * HW_];
        zv.y = zr[(size_t)(lane * 4 + 1) * HW_];
        zv.z = zr[(size_t)(lane * 4 + 2) * HW_];
        zv.w = zr[(size_t)(lane * 4 + 3) * HW_];
        const float zn2a = zn2g[row];
        float bd = INFINITY;
        bk = 0x7fffffff;
        #pragma unroll
        for (int j = 0; j < 4; ++j) {
            u64 mj = msk[j];
            while (mj) {
                const int l = __ffsll((unsigned long long)mj) - 1;
                mj &= mj - 1;
                const u32 val = __shfl(ev[j], l);
                const int k = ((l * 4 + j) >> 1) * 64 + (int)(val & 63u);
                const float4 cv = *(const float4*)(cb + (size_t)k * C_ + lane * 4);
                double s = (double)zv.x * cv.x + (double)zv.y * cv.y
                         + (double)zv.z * cv.z + (double)zv.w * cv.w;
                #pragma unroll
                for (int off = 32; off >= 1; off >>= 1) s += __shfl_xor(s, off);
                const float sf = (float)s;
                const float d = (zn2a + e2g[k]) - 2.0f * sf;
                if (d < bd || (d == bd && k < bk)) { bd = d; bk = k; }
            }
        }
    }
    if (lane == 0) {
        idxg[row] = bk;
        out[8388609 + row] = (float)bk;
    }
}

// =============== z_q (STE mimic) + loss, lane-owns-n mapping =================
// (verified round 15: cb rows read sequentially, z/out coalesced in hw)
__global__ __launch_bounds__(256) void vq_zq_loss_kernel(const float* __restrict__ z,
                                                         const float* __restrict__ cb,
                                                         const int* __restrict__ idxg,
                                                         float* __restrict__ out,
                                                         double* __restrict__ partial) {
    const int lane = threadIdx.x & 63, wid = threadIdx.x >> 6;
    const int n0 = blockIdx.x * 64;
    const int n = n0 + lane;
    const int b = n >> 12;
    const int hw = n & 4095;
    const int k = idxg[n];
    const int c0 = wid * 64;
    const float* cbr = cb + (size_t)k * C_ + c0;
    const float* zb = z + ((size_t)(b * C_ + c0)) * HW_ + hw;
    float* ob = out + ((size_t)(b * C_ + c0)) * HW_ + hw;
    double acc = 0.0;
    #pragma unroll 4
    for (int c = 0; c < 64; c += 4) {
        const float4 cv = *(const float4*)(cbr + c);
        const float z0 = zb[(size_t)(c + 0) * HW_];
        const float z1 = zb[(size_t)(c + 1) * HW_];
        const float z2 = zb[(size_t)(c + 2) * HW_];
        const float z3 = zb[(size_t)(c + 3) * HW_];
        const float t0 = cv.x - z0;
        const float t1 = cv.y - z1;
        const float t2 = cv.z - z2;
        const float t3 = cv.w - z3;
        ob[(size_t)(c + 0) * HW_] = z0 + t0;
        ob[(size_t)(c + 1) * HW_] = z1 + t1;
        ob[(size_t)(c + 2) * HW_] = z2 + t2;
        ob[(size_t)(c + 3) * HW_] = z3 + t3;
        acc += (double)t0 * t0 + (double)t1 * t1 + (double)t2 * t2 + (double)t3 * t3;
    }
    #pragma unroll
    for (int off = 32; off >= 1; off >>= 1) acc += __shfl_xor(acc, off);
    __shared__ double ls[4];
    if (lane == 0) ls[wid] = acc;
    __syncthreads();
    if (threadIdx.x == 0) partial[blockIdx.x] = ls[0] + ls[1] + ls[2] + ls[3];
}

// =============== loss finalize (1 block) =====================================
__global__ __launch_bounds__(256) void vq_loss_final(const double* __restrict__ partial,
                                                     float* __restrict__ out) {
    double acc = 0.0;
    for (int j = threadIdx.x; j < 512; j += 256) acc += partial[j];
    #pragma unroll
    for (int off = 32; off >= 1; off >>= 1) acc += __shfl_xor(acc, off);
    __shared__ double ls[4];
    const int lane = threadIdx.x & 63, wid = threadIdx.x >> 6;
    if (lane == 0) ls[wid] = acc;
    __syncthreads();
    if (threadIdx.x == 0)
        out[8388608] = (float)(1.25 * (ls[0] + ls[1] + ls[2] + ls[3]) / 8388608.0);
}

// =============== fallback fp64 path (round-1, used if ws too small) ==========
__global__ __launch_bounds__(256) void vq_e2_old(const float* __restrict__ cb,
                                                 float* __restrict__ e2g) {
    int lane = threadIdx.x & 63;
    int w = threadIdx.x >> 6;
    int k = blockIdx.x * 4 + w;
    const float4 v = *reinterpret_cast<const float4*>(cb + (size_t)k * C_ + lane * 4);
    double acc = (double)v.x * v.x + (double)v.y * v.y
               + (double)v.z * v.z + (double)v.w * v.w;
    #pragma unroll
    for (int off = 32; off >= 1; off >>= 1) acc += __shfl_xor(acc, off);
    if (lane == 0) e2g[k] = (float)acc;
}

__global__ __launch_bounds__(256) void vq_zn2_old(const float* __restrict__ z,
                                                  float* __restrict__ zn2g) {
    int n = blockIdx.x * 256 + threadIdx.x;
    int b = n >> 12;
    int hw = n & 4095;
    const float* p = z + (size_t)b * C_ * HW_ + hw;
    double acc = 0.0;
    #pragma unroll 8
    for (int c = 0; c < C_; ++c) {
        float v = p[(size_t)c * HW_];
        acc += (double)v * (double)v;
    }
    zn2g[n] = (float)acc;
}

__global__ __launch_bounds__(256) void vq_argmin_old(const float* __restrict__ z,
                                                     const float* __restrict__ cb,
                                                     const float* __restrict__ e2g,
                                                     const float* __restrict__ zn2g,
                                                     int* __restrict__ idxg) {
    __shared__ float zt[C_][32];
    __shared__ float et[64][64];
    const int tid = threadIdx.x;
    const int n0 = blockIdx.x * 32;
    const int b = n0 >> 12;
    const int hw0 = n0 & 4095;
    {
        const int nn = tid & 31;
        const int c8 = tid >> 5;
        #pragma unroll
        for (int j = 0; j < 32; ++j) {
            const int c = j * 8 + c8;
            zt[c][nn] = z[(size_t)(b * C_ + c) * HW_ + hw0 + nn];
        }
    }
    const int cg = tid & 15;
    const int rg = tid >> 4;
    const int r0 = rg * 2;
    __syncthreads();
    const float zn2a = zn2g[n0 + r0];
    const float zn2b = zn2g[n0 + r0 + 1];
    float dmin0 = INFINITY, dmin1 = INFINITY;
    int imin0 = 0, imin1 = 0;
    const int kk = tid >> 2;
    const int c4 = (tid & 3) * 16;
    for (int kt = 0; kt < K_; kt += 64) {
        double s00 = 0, s01 = 0, s02 = 0, s03 = 0;
        double s10 = 0, s11 = 0, s12 = 0, s13 = 0;
        for (int cc = 0; cc < C_; cc += 64) {
            __syncthreads();
            {
                const float* src = cb + (size_t)(kt + kk) * C_ + cc + c4;
                #pragma unroll
                for (int j = 0; j < 16; j += 4) {
                    const float4 v = *reinterpret_cast<const float4*>(src + j);
                    et[c4 + j + 0][kk] = v.x;
                    et[c4 + j + 1][kk] = v.y;
                    et[c4 + j + 2][kk] = v.z;
                    et[c4 + j + 3][kk] = v.w;
                }
            }
            __syncthreads();
            #pragma unroll 4
            for (int c2 = 0; c2 < 64; ++c2) {
                const float2 zv = *reinterpret_cast<const float2*>(&zt[cc + c2][r0]);
                const float4 ev = *reinterpret_cast<const float4*>(&et[c2][cg * 4]);
                const double z0 = (double)zv.x, z1 = (double)zv.y;
                s00 += z0 * ev.x; s01 += z0 * ev.y; s02 += z0 * ev.z; s03 += z0 * ev.w;
                s10 += z1 * ev.x; s11 += z1 * ev.y; s12 += z1 * ev.z; s13 += z1 * ev.w;
            }
        }
        const int kbase = kt + cg * 4;
        const float sf0[4] = {(float)s00, (float)s01, (float)s02, (float)s03};
        const float sf1[4] = {(float)s10, (float)s11, (float)s12, (float)s13};
        #pragma unroll
        for (int j = 0; j < 4; ++j) {
            const int k = kbase + j;
            const float e2k = e2g[k];
            const float d0 = (zn2a + e2k) - 2.0f * sf0[j];
            const float d1 = (zn2b + e2k) - 2.0f * sf1[j];
            if (d0 < dmin0) { dmin0 = d0; imin0 = k; }
            if (d1 < dmin1) { dmin1 = d1; imin1 = k; }
        }
    }
    #pragma unroll
    for (int off = 8; off >= 1; off >>= 1) {
        const float od0 = __shfl_xor(dmin0, off);
        const int   oi0 = __shfl_xor(imin0, off);
        const float od1 = __shfl_xor(dmin1, off);
        const int   oi1 = __shfl_xor(imin1, off);
        if (od0 < dmin0 || (od0 == dmin0 && oi0 < imin0)) { dmin0 = od0; imin0 = oi0; }
        if (od1 < dmin1 || (od1 == dmin1 && oi1 < imin1)) { dmin1 = od1; imin1 = oi1; }
    }
    if (cg == 0) {
        idxg[n0 + r0]     = imin0;
        idxg[n0 + r0 + 1] = imin1;
    }
}

__global__ __launch_bounds__(256) void vq_final_old(const int* __restrict__ idxg,
                                                    float* __restrict__ out) {
    const int i = blockIdx.x * 256 + threadIdx.x;
    out[8388609 + i] = (float)idxg[i];
}

__global__ __launch_bounds__(256) void vq_zq_loss_old(const float* __restrict__ z,
                                                      const float* __restrict__ cb,
                                                      const int* __restrict__ idxg,
                                                      float* __restrict__ out,
                                                      double* __restrict__ partial) {
    double acc = 0.0;
    for (size_t i4 = (size_t)blockIdx.x * 256 + threadIdx.x; i4 < 2097152ULL;
         i4 += 512ULL * 256ULL) {
        const size_t i = i4 * 4;
        const int hw = (int)(i & 4095);
        const int bc = (int)(i >> 12);
        const int c = bc & 255;
        const int b = bc >> 8;
        const int n = (b << 12) + hw;
        const float4 zv = *(const float4*)(z + i);
        const int k0 = idxg[n], k1 = idxg[n + 1], k2 = idxg[n + 2], k3 = idxg[n + 3];
        const float t0 = cb[(size_t)k0 * C_ + c] - zv.x;
        const float t1 = cb[(size_t)k1 * C_ + c] - zv.y;
        const float t2 = cb[(size_t)k2 * C_ + c] - zv.z;
        const float t3 = cb[(size_t)k3 * C_ + c] - zv.w;
        float4 o = { zv.x + t0, zv.y + t1, zv.z + t2, zv.w + t3 };
        *(float4*)(out + i) = o;
        acc += (double)t0 * t0 + (double)t1 * t1 + (double)t2 * t2 + (double)t3 * t3;
    }
    #pragma unroll
    for (int off = 32; off >= 1; off >>= 1) acc += __shfl_xor(acc, off);
    __shared__ double ls[4];
    const int lane = threadIdx.x & 63, wid = threadIdx.x >> 6;
    if (lane == 0) ls[wid] = acc;
    __syncthreads();
    if (threadIdx.x == 0) partial[blockIdx.x] = ls[0] + ls[1] + ls[2] + ls[3];
}

extern "C" void kernel_launch(void* const* d_in, const int* in_sizes, int n_in,
                              void* d_out, int out_size, void* d_ws, size_t ws_size,
                              hipStream_t stream) {
    const float* z  = (const float*)d_in[0];
    const float* cb = (const float*)d_in[1];
    float* out = (float*)d_out;
    char* ws = (char*)d_ws;

    double* lossp = (double*)(ws + O_LOSSP);
    float*  e2g  = (float*)(ws + O_E2);
    float*  zn2g = (float*)(ws + O_ZN2);
    int*    idxg = (int*)(ws + O_IDX);

    if (ws_size >= WS_NEED) {
        u16*   Ap   = (u16*)(ws + O_AP);
        u16*   Bp   = (u16*)(ws + O_BP);
        u32*   cand = (u32*)(ws + O_CAND);

        hipLaunchKernelGGL(vq_prep, dim3(640), dim3(256), 0, stream,
                           z, cb, Ap, Bp, zn2g, e2g);
        hipLaunchKernelGGL(vq_gemm_top2, dim3(16384), dim3(256), 0, stream, Ap, Bp, cand);
        hipLaunchKernelGGL(vq_pick, dim3(N_ / 4), dim3(256), 0, stream,
                           cand, z, cb, e2g, zn2g, idxg, out);
        hipLaunchKernelGGL(vq_zq_loss_kernel, dim3(512), dim3(256), 0, stream,
                           z, cb, idxg, out, lossp);
    } else {
        hipLaunchKernelGGL(vq_e2_old, dim3(K_ / 4), dim3(256), 0, stream, cb, e2g);
        hipLaunchKernelGGL(vq_zn2_old, dim3(N_ / 256), dim3(256), 0, stream, z, zn2g);
        hipLaunchKernelGGL(vq_argmin_old, dim3(N_ / 32), dim3(256), 0, stream,
                           z, cb, e2g, zn2g, idxg);
        hipLaunchKernelGGL(vq_final_old, dim3(N_ / 256), dim3(256), 0, stream, idxg, out);
        hipLaunchKernelGGL(vq_zq_loss_old, dim3(512), dim3(256), 0, stream,
                           z, cb, idxg, out, lossp);
    }

    hipLaunchKernelGGL(vq_loss_final, dim3(1), dim3(256), 0, stream, lossp, out);
}

// Round 17
// 205.828 us; speedup vs baseline: 1.0356x; 1.0356x over previous
//
#include <hip/hip_runtime.h>
#include <hip/hip_bf16.h>
#include <math.h>

typedef unsigned short u16;
typedef unsigned int u32;
typedef unsigned long long u64;
typedef __attribute__((ext_vector_type(8))) _Float16 f16x8;
typedef __attribute__((ext_vector_type(4))) float f32x4;

#define B_   8
#define C_   256
#define HW_  4096
#define N_   32768
#define K_   8192

// ---- ws layout (bytes) ----
#define O_LOSSP 0ULL            // 512 doubles
#define O_E2    16384ULL        // 8192 f32
#define O_ZN2   49152ULL        // 32768 f32
#define O_IDX   180224ULL       // 32768 i32
#define O_AP    311296ULL       // 256 tiles * 8 chunks * 8KB (f16)
#define O_BP    17088512ULL     // 64 tiles * 8 chunks * 8KB (f16)
#define O_CAND  21282816ULL     // 32768*128*2 u32
#define WS_NEED 54837248ULL

#define THRESH_T 9e-5f

// LDS/tile byte swizzle: slot(row) = (row>>1)&3. Store K-group u4 at byte
// (u4*16)^(GSWZ(r)<<4); read group g at (g*16)^(GSWZ(r)<<4).
// Conflict-free for the 16-row fragment ds_read pattern (r8: BANK_CONFLICT=0).
#define GSWZ(r) (((r) >> 1) & 3)

__device__ __forceinline__ u16 f2h(float f) {
    _Float16 h = (_Float16)f;                 // v_cvt_f16_f32, RNE, deterministic
    return __builtin_bit_cast(u16, h);
}

__device__ __forceinline__ void gload16(const void* g, void* l) {
    __builtin_amdgcn_global_load_lds((const __attribute__((address_space(1))) void*)g,
                                     (__attribute__((address_space(3))) void*)l, 16, 0, 0);
}

// Tile layout (both Ap and Bp): [tile(128 rows)][chunk kc8 of 8][128 rows x 64B]

// =============== fused prep: blocks 0..127 -> codebook, 128..639 -> z ========
// (verified rounds 9-15)
__global__ __launch_bounds__(256) void vq_prep(const float* __restrict__ z,
                                               const float* __restrict__ cb,
                                               u16* __restrict__ Ap,
                                               u16* __restrict__ Bp,
                                               float* __restrict__ zn2g,
                                               float* __restrict__ e2g) {
    __shared__ float zl[128][65];
    const int tid = threadIdx.x;

    if (blockIdx.x < 128) {
        // ---- prep_cb: B_prep f16 (e scaled 2^13) + e2 ----
        const int k0 = blockIdx.x * 64;
        const int r = tid >> 2;
        const int u4 = tid & 3;
        const int k = k0 + r;
        const int r7 = k & 127;
        double eacc = 0.0;
        #pragma unroll
        for (int kc8 = 0; kc8 < 8; ++kc8) {
            const float* src = cb + (size_t)k * C_ + kc8 * 32 + u4 * 8;
            float4 v0 = *(const float4*)(src);
            float4 v1 = *(const float4*)(src + 4);
            float vals[8] = { v0.x, v0.y, v0.z, v0.w, v1.x, v1.y, v1.z, v1.w };
            u16 tmp[8];
            #pragma unroll
            for (int j = 0; j < 8; ++j) {
                eacc += (double)vals[j] * (double)vals[j];
                tmp[j] = f2h(vals[j] * 8192.0f);   // exact pow2 scale, then RNE
            }
            char* dst = (char*)Bp + ((size_t)((k >> 7) * 8 + kc8)) * 8192
                      + r7 * 64 + ((u4 * 16) ^ (GSWZ(r7) << 4));
            *(uint4*)dst = *(uint4*)tmp;
        }
        eacc += __shfl_xor(eacc, 1);
        eacc += __shfl_xor(eacc, 2);
        if (u4 == 0) e2g[k] = (float)eacc;
        return;
    }

    // ---- prep_z: A_prep f16 + zn2 ----
    const int bidz = blockIdx.x - 128;            // 0..511
    const int bb = bidz >> 6;
    const int hwc = bidz & 63;
    const int hw0 = hwc * 64;
    const int n0 = bb * HW_ + hw0;
    const int r = tid >> 2;         // 0..63 row within block
    const int u4 = tid & 3;         // K-group slot
    const int n = n0 + r;
    const int r7 = n & 127;         // row within 128-row tile
    double zacc = 0.0;

    for (int h = 0; h < 2; ++h) {
        __syncthreads();
        for (int c0 = 0; c0 < 128; c0 += 4) {
            int c = c0 + (tid >> 6);
            zl[c][tid & 63] = z[((size_t)(bb * C_ + h * 128 + c)) * HW_ + hw0 + (tid & 63)];
        }
        __syncthreads();
        // Ap chunks kc8 = h*4 + q ; local c = q*32 + u4*8 + j
        #pragma unroll
        for (int q = 0; q < 4; ++q) {
            u16 tmp[8];
            #pragma unroll
            for (int j = 0; j < 8; ++j) {
                float f = zl[q * 32 + u4 * 8 + j][r];
                zacc += (double)f * (double)f;
                tmp[j] = f2h(f);
            }
            char* dst = (char*)Ap + ((size_t)((n >> 7) * 8 + h * 4 + q)) * 8192
                      + r7 * 64 + ((u4 * 16) ^ (GSWZ(r7) << 4));
            *(uint4*)dst = *(uint4*)tmp;
        }
    }
    // reduce zn2 across the 4 u4-lanes of each row
    zacc += __shfl_xor(zacc, 1);
    zacc += __shfl_xor(zacc, 2);
    if (u4 == 0) zn2g[n] = (float)zacc;
}

// =============== main f16 MFMA scorer: top-2 per (row, 64-codes) =============
// Round-8 champion verbatim: 128 codes x 128 rows, 4 waves (2x2), BK=32,
// 32KB dbuf LDS, ONE __syncthreads per chunk. Measured 152us, MfmaUtil 45%,
// BANK_CONFLICT 0 (~904 TF = the 2-barrier-class structural ceiling; six
// structural variants r8/r10/r11/r12/r13/r16 all confirm this plateau).
__global__ __launch_bounds__(256) void vq_gemm_top2(const u16* __restrict__ Ap,
                                                    const u16* __restrict__ Bp,
                                                    u32* __restrict__ cand) {
    __shared__ char lds[32768];          // 2 bufs x {codes 8K, z 8K}
    const int tid = threadIdx.x;
    const int lane = tid & 63, wid = tid >> 6;
    const int wm = wid >> 1, wn = wid & 1;
    const int l15 = lane & 15, l4 = lane >> 4;

    // L2-aware order: XCD owns 8 n_tiles; 8 consecutive blocks share one m-tile.
    const int raw = blockIdx.x;
    const int m_tile = raw >> 6;                         // 0..255
    const int n_tile = (raw & 7) * 8 + ((raw >> 3) & 7); // 0..63

    f32x4 acc[4][4];
    #pragma unroll
    for (int i = 0; i < 4; ++i)
        #pragma unroll
        for (int j = 0; j < 4; ++j) acc[i][j] = (f32x4){0.f, 0.f, 0.f, 0.f};

    int rc[4], rz[4], xc[4], xz[4];
    #pragma unroll
    for (int f = 0; f < 4; ++f) {
        rc[f] = wm * 64 + f * 16 + l15;
        rz[f] = wn * 64 + f * 16 + l15;
        xc[f] = GSWZ(rc[f]) << 4;
        xz[f] = GSWZ(rz[f]) << 4;
    }
    const int ob = l4 * 16;

    const char* codes_src = (const char*)Bp + (size_t)n_tile * 65536;
    const char* z_src     = (const char*)Ap + (size_t)m_tile * 65536;

    #define STAGE(buf, kc)                                                        \
        do {                                                                      \
            const char* cs_ = codes_src + (size_t)(kc) * 8192;                    \
            const char* zs_ = z_src + (size_t)(kc) * 8192;                        \
            char* lb_ = lds + (buf) * 16384;                                      \
            gload16(cs_ + tid * 16, lb_ + tid * 16);                              \
            gload16(cs_ + 4096 + tid * 16, lb_ + 4096 + tid * 16);                \
            gload16(zs_ + tid * 16, lb_ + 8192 + tid * 16);                       \
            gload16(zs_ + 4096 + tid * 16, lb_ + 12288 + tid * 16);               \
        } while (0)

    #define COMPUTE(buf)                                                          \
        do {                                                                      \
            const char* base_ = lds + (buf) * 16384;                              \
            f16x8 la[4], lb[4];                                                   \
            _Pragma("unroll")                                                     \
            for (int f = 0; f < 4; ++f) {                                         \
                la[f] = *(const f16x8*)(base_ + rc[f] * 64 + (ob ^ xc[f]));       \
                lb[f] = *(const f16x8*)(base_ + 8192 + rz[f] * 64 + (ob ^ xz[f]));\
            }                                                                     \
            _Pragma("unroll")                                                     \
            for (int fm = 0; fm < 4; ++fm)                                        \
                _Pragma("unroll")                                                 \
                for (int fn = 0; fn < 4; ++fn)                                    \
                    acc[fm][fn] = __builtin_amdgcn_mfma_f32_16x16x32_f16(         \
                        la[fm], lb[fn], acc[fm][fn], 0, 0, 0);                    \
        } while (0)

    STAGE(0, 0);
    #pragma unroll
    for (int kc = 0; kc < 8; ++kc) {
        __syncthreads();                       // chunk kc landed; prev reads done
        if (kc < 7) STAGE((kc + 1) & 1, kc + 1);
        COMPUTE(kc & 1);
    }

    #undef STAGE
    #undef COMPUTE

    // epilogue: w = 0.5 - s_scaled*2^-12 (positive -> u32 order == float order);
    // clear low 6 mantissa bits, pack 6-bit in-tile idx, track top-2 via min/max.
    const int ktile = n_tile * 2 + wm;
    #pragma unroll
    for (int fn = 0; fn < 4; ++fn) {
        u32 m1 = 0xFFFFFFFFu, m2 = 0xFFFFFFFFu;
        #pragma unroll
        for (int fm = 0; fm < 4; ++fm) {
            #pragma unroll
            for (int rv = 0; rv < 4; ++rv) {
                float w = fmaf(acc[fm][fn][rv], -0x1p-12f, 0.5f);
                u32 p = (__float_as_uint(w) & ~63u) | (u32)(fm * 16 + l4 * 4 + rv);
                u32 t = m1 > p ? m1 : p;
                m1 = m1 < p ? m1 : p;
                m2 = m2 < t ? m2 : t;
            }
        }
        #pragma unroll
        for (int off = 16; off <= 32; off <<= 1) {
            u32 b1 = __shfl_xor(m1, off);
            u32 b2 = __shfl_xor(m2, off);
            u32 t = m1 > b1 ? m1 : b1;
            m1 = m1 < b1 ? m1 : b1;
            u32 s2 = m2 < b2 ? m2 : b2;
            m2 = s2 < t ? s2 : t;
        }
        if (l4 == 0) {
            int rowg = m_tile * 128 + wn * 64 + fn * 16 + l15;
            *(uint2*)(cand + (size_t)rowg * 256 + ktile * 2) = make_uint2(m1, m2);
        }
    }
}

// =============== pick: min + threshold + exact fp64 rescue + idx out =========
// wave per row. Fast path: exactly 1 candidate under thr -> it IS the argmin.
// Slow path reads z directly (strided gather; bit-identical fp64 rescue).
__global__ __launch_bounds__(256) void vq_pick(const u32* __restrict__ cand,
                                               const float* __restrict__ z,
                                               const float* __restrict__ cb,
                                               const float* __restrict__ e2g,
                                               const float* __restrict__ zn2g,
                                               int* __restrict__ idxg,
                                               float* __restrict__ out) {
    const int lane = threadIdx.x & 63, wid = threadIdx.x >> 6;
    const int row = blockIdx.x * 4 + wid;
    const uint4 e = ((const uint4*)(cand + (size_t)row * 256))[lane];
    u32 m = e.x < e.y ? e.x : e.y;
    u32 mzw = e.z < e.w ? e.z : e.w;
    m = m < mzw ? m : mzw;
    #pragma unroll
    for (int off = 32; off >= 1; off >>= 1) {
        u32 o = __shfl_xor(m, off);
        m = o < m ? o : m;
    }
    const float thr = __uint_as_float(m & ~63u) + THRESH_T;
    const u32 ev[4] = { e.x, e.y, e.z, e.w };
    u64 msk[4];
    int tot = 0;
    #pragma unroll
    for (int j = 0; j < 4; ++j) {
        msk[j] = __ballot(__uint_as_float(ev[j] & ~63u) <= thr);
        tot += __popcll((unsigned long long)msk[j]);
    }
    int bk;
    if (tot == 1) {
        const int j = msk[0] ? 0 : (msk[1] ? 1 : (msk[2] ? 2 : 3));
        const int l = __ffsll((unsigned long long)msk[j]) - 1;
        const u32 val = __shfl(ev[j], l);
        bk = ((l * 4 + j) >> 1) * 64 + (int)(val & 63u);
    } else {
        const int bb = row >> 12;
        const int hw = row & 4095;
        const float* zr = z + (size_t)(bb * C_) * HW_ + hw;
        float4 zv;
        zv.x = zr[(size_t)(lane * 4 + 0) * HW_];
        zv.y = zr[(size_t)(lane * 4 + 1) * HW_];
        zv.z = zr[(size_t)(lane * 4 + 2) * HW_];
        zv.w = zr[(size_t)(lane * 4 + 3) * HW_];
        const float zn2a = zn2g[row];
        float bd = INFINITY;
        bk = 0x7fffffff;
        #pragma unroll
        for (int j = 0; j < 4; ++j) {
            u64 mj = msk[j];
            while (mj) {
                const int l = __ffsll((unsigned long long)mj) - 1;
                mj &= mj - 1;
                const u32 val = __shfl(ev[j], l);
                const int k = ((l * 4 + j) >> 1) * 64 + (int)(val & 63u);
                const float4 cv = *(const float4*)(cb + (size_t)k * C_ + lane * 4);
                double s = (double)zv.x * cv.x + (double)zv.y * cv.y
                         + (double)zv.z * cv.z + (double)zv.w * cv.w;
                #pragma unroll
                for (int off = 32; off >= 1; off >>= 1) s += __shfl_xor(s, off);
                const float sf = (float)s;
                const float d = (zn2a + e2g[k]) - 2.0f * sf;
                if (d < bd || (d == bd && k < bk)) { bd = d; bk = k; }
            }
        }
    }
    if (lane == 0) {
        idxg[row] = bk;
        out[8388609 + row] = (float)bk;
    }
}

// =============== z_q (STE mimic) + loss, lane-owns-n mapping =================
// (verified round 15: cb rows read sequentially, z/out coalesced in hw)
__global__ __launch_bounds__(256) void vq_zq_loss_kernel(const float* __restrict__ z,
                                                         const float* __restrict__ cb,
                                                         const int* __restrict__ idxg,
                                                         float* __restrict__ out,
                                                         double* __restrict__ partial) {
    const int lane = threadIdx.x & 63, wid = threadIdx.x >> 6;
    const int n0 = blockIdx.x * 64;
    const int n = n0 + lane;
    const int b = n >> 12;
    const int hw = n & 4095;
    const int k = idxg[n];
    const int c0 = wid * 64;
    const float* cbr = cb + (size_t)k * C_ + c0;
    const float* zb = z + ((size_t)(b * C_ + c0)) * HW_ + hw;
    float* ob = out + ((size_t)(b * C_ + c0)) * HW_ + hw;
    double acc = 0.0;
    #pragma unroll 4
    for (int c = 0; c < 64; c += 4) {
        const float4 cv = *(const float4*)(cbr + c);
        const float z0 = zb[(size_t)(c + 0) * HW_];
        const float z1 = zb[(size_t)(c + 1) * HW_];
        const float z2 = zb[(size_t)(c + 2) * HW_];
        const float z3 = zb[(size_t)(c + 3) * HW_];
        const float t0 = cv.x - z0;
        const float t1 = cv.y - z1;
        const float t2 = cv.z - z2;
        const float t3 = cv.w - z3;
        ob[(size_t)(c + 0) * HW_] = z0 + t0;
        ob[(size_t)(c + 1) * HW_] = z1 + t1;
        ob[(size_t)(c + 2) * HW_] = z2 + t2;
        ob[(size_t)(c + 3) * HW_] = z3 + t3;
        acc += (double)t0 * t0 + (double)t1 * t1 + (double)t2 * t2 + (double)t3 * t3;
    }
    #pragma unroll
    for (int off = 32; off >= 1; off >>= 1) acc += __shfl_xor(acc, off);
    __shared__ double ls[4];
    if (lane == 0) ls[wid] = acc;
    __syncthreads();
    if (threadIdx.x == 0) partial[blockIdx.x] = ls[0] + ls[1] + ls[2] + ls[3];
}

// =============== loss finalize (1 block) =====================================
__global__ __launch_bounds__(256) void vq_loss_final(const double* __restrict__ partial,
                                                     float* __restrict__ out) {
    double acc = 0.0;
    for (int j = threadIdx.x; j < 512; j += 256) acc += partial[j];
    #pragma unroll
    for (int off = 32; off >= 1; off >>= 1) acc += __shfl_xor(acc, off);
    __shared__ double ls[4];
    const int lane = threadIdx.x & 63, wid = threadIdx.x >> 6;
    if (lane == 0) ls[wid] = acc;
    __syncthreads();
    if (threadIdx.x == 0)
        out[8388608] = (float)(1.25 * (ls[0] + ls[1] + ls[2] + ls[3]) / 8388608.0);
}

// =============== fallback fp64 path (round-1, used if ws too small) ==========
__global__ __launch_bounds__(256) void vq_e2_old(const float* __restrict__ cb,
                                                 float* __restrict__ e2g) {
    int lane = threadIdx.x & 63;
    int w = threadIdx.x >> 6;
    int k = blockIdx.x * 4 + w;
    const float4 v = *reinterpret_cast<const float4*>(cb + (size_t)k * C_ + lane * 4);
    double acc = (double)v.x * v.x + (double)v.y * v.y
               + (double)v.z * v.z + (double)v.w * v.w;
    #pragma unroll
    for (int off = 32; off >= 1; off >>= 1) acc += __shfl_xor(acc, off);
    if (lane == 0) e2g[k] = (float)acc;
}

__global__ __launch_bounds__(256) void vq_zn2_old(const float* __restrict__ z,
                                                  float* __restrict__ zn2g) {
    int n = blockIdx.x * 256 + threadIdx.x;
    int b = n >> 12;
    int hw = n & 4095;
    const float* p = z + (size_t)b * C_ * HW_ + hw;
    double acc = 0.0;
    #pragma unroll 8
    for (int c = 0; c < C_; ++c) {
        float v = p[(size_t)c * HW_];
        acc += (double)v * (double)v;
    }
    zn2g[n] = (float)acc;
}

__global__ __launch_bounds__(256) void vq_argmin_old(const float* __restrict__ z,
                                                     const float* __restrict__ cb,
                                                     const float* __restrict__ e2g,
                                                     const float* __restrict__ zn2g,
                                                     int* __restrict__ idxg) {
    __shared__ float zt[C_][32];
    __shared__ float et[64][64];
    const int tid = threadIdx.x;
    const int n0 = blockIdx.x * 32;
    const int b = n0 >> 12;
    const int hw0 = n0 & 4095;
    {
        const int nn = tid & 31;
        const int c8 = tid >> 5;
        #pragma unroll
        for (int j = 0; j < 32; ++j) {
            const int c = j * 8 + c8;
            zt[c][nn] = z[(size_t)(b * C_ + c) * HW_ + hw0 + nn];
        }
    }
    const int cg = tid & 15;
    const int rg = tid >> 4;
    const int r0 = rg * 2;
    __syncthreads();
    const float zn2a = zn2g[n0 + r0];
    const float zn2b = zn2g[n0 + r0 + 1];
    float dmin0 = INFINITY, dmin1 = INFINITY;
    int imin0 = 0, imin1 = 0;
    const int kk = tid >> 2;
    const int c4 = (tid & 3) * 16;
    for (int kt = 0; kt < K_; kt += 64) {
        double s00 = 0, s01 = 0, s02 = 0, s03 = 0;
        double s10 = 0, s11 = 0, s12 = 0, s13 = 0;
        for (int cc = 0; cc < C_; cc += 64) {
            __syncthreads();
            {
                const float* src = cb + (size_t)(kt + kk) * C_ + cc + c4;
                #pragma unroll
                for (int j = 0; j < 16; j += 4) {
                    const float4 v = *reinterpret_cast<const float4*>(src + j);
                    et[c4 + j + 0][kk] = v.x;
                    et[c4 + j + 1][kk] = v.y;
                    et[c4 + j + 2][kk] = v.z;
                    et[c4 + j + 3][kk] = v.w;
                }
            }
            __syncthreads();
            #pragma unroll 4
            for (int c2 = 0; c2 < 64; ++c2) {
                const float2 zv = *reinterpret_cast<const float2*>(&zt[cc + c2][r0]);
                const float4 ev = *reinterpret_cast<const float4*>(&et[c2][cg * 4]);
                const double z0 = (double)zv.x, z1 = (double)zv.y;
                s00 += z0 * ev.x; s01 += z0 * ev.y; s02 += z0 * ev.z; s03 += z0 * ev.w;
                s10 += z1 * ev.x; s11 += z1 * ev.y; s12 += z1 * ev.z; s13 += z1 * ev.w;
            }
        }
        const int kbase = kt + cg * 4;
        const float sf0[4] = {(float)s00, (float)s01, (float)s02, (float)s03};
        const float sf1[4] = {(float)s10, (float)s11, (float)s12, (float)s13};
        #pragma unroll
        for (int j = 0; j < 4; ++j) {
            const int k = kbase + j;
            const float e2k = e2g[k];
            const float d0 = (zn2a + e2k) - 2.0f * sf0[j];
            const float d1 = (zn2b + e2k) - 2.0f * sf1[j];
            if (d0 < dmin0) { dmin0 = d0; imin0 = k; }
            if (d1 < dmin1) { dmin1 = d1; imin1 = k; }
        }
    }
    #pragma unroll
    for (int off = 8; off >= 1; off >>= 1) {
        const float od0 = __shfl_xor(dmin0, off);
        const int   oi0 = __shfl_xor(imin0, off);
        const float od1 = __shfl_xor(dmin1, off);
        const int   oi1 = __shfl_xor(imin1, off);
        if (od0 < dmin0 || (od0 == dmin0 && oi0 < imin0)) { dmin0 = od0; imin0 = oi0; }
        if (od1 < dmin1 || (od1 == dmin1 && oi1 < imin1)) { dmin1 = od1; imin1 = oi1; }
    }
    if (cg == 0) {
        idxg[n0 + r0]     = imin0;
        idxg[n0 + r0 + 1] = imin1;
    }
}

__global__ __launch_bounds__(256) void vq_final_old(const int* __restrict__ idxg,
                                                    float* __restrict__ out) {
    const int i = blockIdx.x * 256 + threadIdx.x;
    out[8388609 + i] = (float)idxg[i];
}

__global__ __launch_bounds__(256) void vq_zq_loss_old(const float* __restrict__ z,
                                                      const float* __restrict__ cb,
                                                      const int* __restrict__ idxg,
                                                      float* __restrict__ out,
                                                      double* __restrict__ partial) {
    double acc = 0.0;
    for (size_t i4 = (size_t)blockIdx.x * 256 + threadIdx.x; i4 < 2097152ULL;
         i4 += 512ULL * 256ULL) {
        const size_t i = i4 * 4;
        const int hw = (int)(i & 4095);
        const int bc = (int)(i >> 12);
        const int c = bc & 255;
        const int b = bc >> 8;
        const int n = (b << 12) + hw;
        const float4 zv = *(const float4*)(z + i);
        const int k0 = idxg[n], k1 = idxg[n + 1], k2 = idxg[n + 2], k3 = idxg[n + 3];
        const float t0 = cb[(size_t)k0 * C_ + c] - zv.x;
        const float t1 = cb[(size_t)k1 * C_ + c] - zv.y;
        const float t2 = cb[(size_t)k2 * C_ + c] - zv.z;
        const float t3 = cb[(size_t)k3 * C_ + c] - zv.w;
        float4 o = { zv.x + t0, zv.y + t1, zv.z + t2, zv.w + t3 };
        *(float4*)(out + i) = o;
        acc += (double)t0 * t0 + (double)t1 * t1 + (double)t2 * t2 + (double)t3 * t3;
    }
    #pragma unroll
    for (int off = 32; off >= 1; off >>= 1) acc += __shfl_xor(acc, off);
    __shared__ double ls[4];
    const int lane = threadIdx.x & 63, wid = threadIdx.x >> 6;
    if (lane == 0) ls[wid] = acc;
    __syncthreads();
    if (threadIdx.x == 0) partial[blockIdx.x] = ls[0] + ls[1] + ls[2] + ls[3];
}

extern "C" void kernel_launch(void* const* d_in, const int* in_sizes, int n_in,
                              void* d_out, int out_size, void* d_ws, size_t ws_size,
                              hipStream_t stream) {
    const float* z  = (const float*)d_in[0];
    const float* cb = (const float*)d_in[1];
    float* out = (float*)d_out;
    char* ws = (char*)d_ws;

    double* lossp = (double*)(ws + O_LOSSP);
    float*  e2g  = (float*)(ws + O_E2);
    float*  zn2g = (float*)(ws + O_ZN2);
    int*    idxg = (int*)(ws + O_IDX);

    if (ws_size >= WS_NEED) {
        u16*   Ap   = (u16*)(ws + O_AP);
        u16*   Bp   = (u16*)(ws + O_BP);
        u32*   cand = (u32*)(ws + O_CAND);

        hipLaunchKernelGGL(vq_prep, dim3(640), dim3(256), 0, stream,
                           z, cb, Ap, Bp, zn2g, e2g);
        hipLaunchKernelGGL(vq_gemm_top2, dim3(16384), dim3(256), 0, stream, Ap, Bp, cand);
        hipLaunchKernelGGL(vq_pick, dim3(N_ / 4), dim3(256), 0, stream,
                           cand, z, cb, e2g, zn2g, idxg, out);
        hipLaunchKernelGGL(vq_zq_loss_kernel, dim3(512), dim3(256), 0, stream,
                           z, cb, idxg, out, lossp);
    } else {
        hipLaunchKernelGGL(vq_e2_old, dim3(K_ / 4), dim3(256), 0, stream, cb, e2g);
        hipLaunchKernelGGL(vq_zn2_old, dim3(N_ / 256), dim3(256), 0, stream, z, zn2g);
        hipLaunchKernelGGL(vq_argmin_old, dim3(N_ / 32), dim3(256), 0, stream,
                           z, cb, e2g, zn2g, idxg);
        hipLaunchKernelGGL(vq_final_old, dim3(N_ / 256), dim3(256), 0, stream, idxg, out);
        hipLaunchKernelGGL(vq_zq_loss_old, dim3(512), dim3(256), 0, stream,
                           z, cb, idxg, out, lossp);
    }

    hipLaunchKernelGGL(vq_loss_final, dim3(1), dim3(256), 0, stream, lossp, out);
}